// Round 10
// baseline (108.836 us; speedup 1.0000x reference)
//
#include <hip/hip_runtime.h>
#include <hip/hip_bf16.h>

typedef __attribute__((ext_vector_type(8))) short short8;
typedef __attribute__((ext_vector_type(4))) float floatx4;

#define TINV 14.2857142857142857f                // 1/0.07
#define LN2  0.6931471805599453f
#define SQS  4.539816022451927f                  // sqrt(TINV*log2 e): dots land in log2-softmax domain
#define NROWS 8192
#define NDIM 128
#define NCH 16                                   // 16 chunks x 512 cols
#define NITS 16                                  // 16 x 32 cols per chunk
#define CLASS_COEF (1.0f / (8192.0f * 3.0f))
#define NOISE_RAW_COEF (-(TINV * TINV) / (57344.0f * 3.0f))

__device__ __forceinline__ float fexp2(float x) {
#if __has_builtin(__builtin_amdgcn_exp2f)
    return __builtin_amdgcn_exp2f(x);
#else
    return __expf(x * LN2);
#endif
}

// fp32 -> bf16 (pre-scaled) transposed into fbT[(kc*8192+row)], 16B chunks, kc=k/8.
// Block 0: pcount + zero out. Block 1: zero S.
__global__ void prep_kernel(const float* __restrict__ in, const int* __restrict__ labels,
                            unsigned short* __restrict__ fbT, float* __restrict__ pcount,
                            float* __restrict__ S, float* __restrict__ out) {
    const int tid = threadIdx.x;
    const int i = blockIdx.x * 256 + tid;       // 512 blocks: 131072 = 8192 rows x 16 kc
    const int kc = i & 15;
    const int row = i >> 4;
    const float4* p = (const float4*)(in + (size_t)row * NDIM + kc * 8);
    const float4 a = p[0], b = p[1];
    union { short8 s; __hip_bfloat162 h[4]; } t;
    t.h[0] = __float22bfloat162_rn(float2{a.x * SQS, a.y * SQS});
    t.h[1] = __float22bfloat162_rn(float2{a.z * SQS, a.w * SQS});
    t.h[2] = __float22bfloat162_rn(float2{b.x * SQS, b.y * SQS});
    t.h[3] = __float22bfloat162_rn(float2{b.z * SQS, b.w * SQS});
    ((short8*)fbT)[(size_t)kc * NROWS + row] = t.s;

    if (blockIdx.x == 0) {
        __shared__ int lab[512];
        lab[tid] = labels[tid];
        lab[tid + 256] = labels[tid + 256];
        if (tid == 0) out[0] = 0.0f;
        __syncthreads();
        #pragma unroll 2
        for (int bb = tid; bb < 512; bb += 256) {
            const int my = lab[bb];
            int cnt = 0;
            #pragma unroll 8
            for (int k = 0; k < 512; ++k) cnt += (lab[k] == my) ? 1 : 0;
            pcount[bb] = 16.0f * (float)(cnt - 1);
        }
    } else if (blockIdx.x == 1) {
        #pragma unroll
        for (int k = tid; k < 16 * NDIM; k += 256) S[k] = 0.0f;
    }
}

// 128 blocks x 256: per 64 rows compute group sums G (8x128), batch sums B (4x128),
// and atomically accumulate class sums S (16x128). fp32 from original features.
__global__ void sums_kernel(const float* __restrict__ in, const int* __restrict__ labels,
                            float* __restrict__ B, float* __restrict__ G,
                            float* __restrict__ S) {
    const int tid = threadIdx.x;
    const int d = tid & 127;
    const int half = tid >> 7;                 // rows half*32 .. half*32+31
    const int rowBase = blockIdx.x * 64;
    float g[4] = {0.0f, 0.0f, 0.0f, 0.0f};
    #pragma unroll
    for (int i = 0; i < 32; ++i) {
        const int r = rowBase + half * 32 + i;
        g[i >> 3] += in[(size_t)r * NDIM + d];
    }
    const int gBase = (rowBase >> 3) + (half << 2);
    #pragma unroll
    for (int k = 0; k < 4; ++k) G[(size_t)(gBase + k) * NDIM + d] = g[k];
    const float b0 = g[0] + g[1], b1 = g[2] + g[3];
    const int bBase = (rowBase >> 4) + (half << 1);
    B[(size_t)bBase * NDIM + d] = b0;
    B[(size_t)(bBase + 1) * NDIM + d] = b1;
    atomicAdd(&S[(size_t)labels[bBase] * NDIM + d], b0);
    atomicAdd(&S[(size_t)(labels[bBase + 1]) * NDIM + d], b1);
}

// grid 2048: rb = blockIdx&127 (64 rows), q = blockIdx>>7 (512-col chunk).
// Pure masked online-softmax: no labels, no possum, no noise (hoisted to final).
// NOTE: register cliff — 32-rows/wave variants spilled (R6-R8, 0.4-1.0 GB HBM).
// NOTE: no device-scope fences/atomics in hot loop; (256,4) only.
__global__ __launch_bounds__(256, 4) void supcon_main(
    const unsigned short* __restrict__ fbT,
    float* __restrict__ sM, float* __restrict__ sS)
{
    __shared__ __align__(16) short stage[2][16 * 32 * 8];   // [buf][kc][col] 16B units, 8KB each

    const int rb = blockIdx.x & 127;
    const int q  = blockIdx.x >> 7;
    const int rowBase = rb << 6;       // 64 rows per block
    const int colBase = q << 9;        // 512 cols per chunk
    const int tid = threadIdx.x;
    const int w = tid >> 6;
    const int lane = tid & 63;
    const int l15 = lane & 15;
    const int l4  = lane >> 4;
    const int kc_hi = lane >> 5;
    const int col_l = lane & 31;

    const short8* fb8 = (const short8*)fbT;

#define ISSUE(IT, BUF)                                                                   \
    {                                                                                    \
        unsigned short* sbase = (unsigned short*)&stage[BUF][0];                         \
        _Pragma("unroll")                                                                \
        for (int j = 0; j < 2; ++j) {                                                    \
            const int kcb = (w << 2) + (j << 1);                                         \
            const unsigned short* src = fbT +                                            \
                ((size_t)(kcb + kc_hi) * NROWS + colBase + ((IT) << 5) + col_l) * 8;     \
            __builtin_amdgcn_global_load_lds(                                            \
                (const __attribute__((address_space(1))) unsigned int*)src,              \
                (__attribute__((address_space(3))) unsigned int*)(sbase + kcb * 256),    \
                16, 0, 0);                                                               \
        }                                                                                \
    }

    ISSUE(0, 0)

    // A fragments: wave owns 16 rows; K=128 register-resident (16 VGPRs)
    const int rw = rowBase + w * 16;
    const int brow = rw >> 4;
    short8 afrag[4];
    #pragma unroll
    for (int t = 0; t < 4; ++t)
        afrag[t] = fb8[(size_t)(t * 4 + l4) * NROWS + rw + l15];

    float tm[4], su[4];
    #pragma unroll
    for (int r = 0; r < 4; ++r) { tm[r] = -1e30f; su[r] = 0.0f; }

    __syncthreads();

    for (int it = 0; it < NITS; ++it) {
        if (it + 1 < NITS) ISSUE(it + 1, (it + 1) & 1)

        const short8* stv = (const short8*)stage[it & 1];
        floatx4 vacc[2];
        #pragma unroll
        for (int c = 0; c < 2; ++c) {
            short8 bfrag[4];
            #pragma unroll
            for (int t = 0; t < 4; ++t)
                bfrag[t] = stv[(t * 4 + l4) * 32 + c * 16 + l15];
            floatx4 acc = {0.0f, 0.0f, 0.0f, 0.0f};
            #pragma unroll
            for (int t = 0; t < 4; ++t)
                acc = __builtin_amdgcn_mfma_f32_16x16x32_bf16(afrag[t], bfrag[t], acc, 0, 0, 0);
            vacc[c] = acc;
        }

        const int nt = brow - ((colBase >> 4) + (it << 1));  // same-batch tile idx if in [0,2)
        const bool anyn = ((unsigned)nt) < 2u;               // wave-uniform, rare
        #pragma unroll
        for (int r = 0; r < 4; ++r) {
            const float v0 = vacc[0][r], v1 = vacc[1][r];
            if (!anyn) {
                // branchless online softmax: alpha==1 when max unchanged
                const float tmr = tm[r];
                const float tnm = fmaxf(tmr, fmaxf(v0, v1));
                su[r] = fmaf(su[r], fexp2(tmr - tnm), fexp2(v0 - tnm) + fexp2(v1 - tnm));
                tm[r] = tnm;
            } else {
                const float vv = nt ? v0 : v1;   // the valid (different-batch) tile
                const float tmr = tm[r];
                const float tnm = fmaxf(tmr, vv);
                su[r] = fmaf(su[r], fexp2(tmr - tnm), fexp2(vv - tnm));
                tm[r] = tnm;
            }
        }
        __syncthreads();
    }
#undef ISSUE

    // combine the 16 lane-partials per row via shuffles (l15 groups hold one row)
    #pragma unroll
    for (int r = 0; r < 4; ++r) {
        float tmv = tm[r], suv = su[r];
        #pragma unroll
        for (int off = 1; off < 16; off <<= 1) {
            float om = __shfl_xor(tmv, off);
            float os = __shfl_xor(suv, off);
            float nm = fmaxf(tmv, om);
            suv = suv * fexp2(tmv - nm) + os * fexp2(om - nm);
            tmv = nm;
        }
        if (l15 == 0) {
            int row = rw + (l4 << 2) + r;
            sM[row * NCH + q] = tmv;
            sS[row * NCH + q] = suv;
        }
    }
}

// 32 blocks x 256 threads: per-row merge over 16 chunks + possum/noise dots; atomicAdd
__global__ __launch_bounds__(256) void final_k(
    const float* __restrict__ sM, const float* __restrict__ sS,
    const float* __restrict__ feat, const int* __restrict__ labels,
    const float* __restrict__ pcount,
    const float* __restrict__ B, const float* __restrict__ G, const float* __restrict__ S,
    float* __restrict__ out)
{
    __shared__ float red[256];
    const int tid = threadIdx.x;
    const int row = blockIdx.x * 256 + tid;

    const float4* M4 = (const float4*)(sM + (size_t)row * NCH);
    const float4* S4 = (const float4*)(sS + (size_t)row * NCH);
    float gm = -1e30f, gs = 0.0f;
    #pragma unroll
    for (int j = 0; j < 4; ++j) {
        const float4 m = M4[j], s = S4[j];
        float nm = fmaxf(fmaxf(gm, m.x), fmaxf(fmaxf(m.y, m.z), m.w));
        gs = gs * fexp2(gm - nm)
           + s.x * fexp2(m.x - nm) + s.y * fexp2(m.y - nm)
           + s.z * fexp2(m.z - nm) + s.w * fexp2(m.w - nm);
        gm = nm;
    }

    const int b = row >> 4;
    const int g = row >> 3;
    const int l = labels[b];
    const float4* F4 = (const float4*)(feat + (size_t)row * NDIM);
    const float4* Sc = (const float4*)(S + (size_t)l * NDIM);
    const float4* Bc = (const float4*)(B + (size_t)b * NDIM);
    const float4* Gc = (const float4*)(G + (size_t)g * NDIM);
    float pos = 0.0f, noi = 0.0f;
    #pragma unroll
    for (int j = 0; j < 32; ++j) {
        const float4 f = F4[j], sv = Sc[j], bv = Bc[j], gv = Gc[j];
        pos += f.x * (sv.x - bv.x) + f.y * (sv.y - bv.y)
             + f.z * (sv.z - bv.z) + f.w * (sv.w - bv.w);
        noi += f.x * (gv.x - f.x) + f.y * (gv.y - f.y)
             + f.z * (gv.z - f.z) + f.w * (gv.w - f.w);
    }

    const float P = pcount[b];
    // L_i (natural log) = LN2*(gm + log2 gs); possum natural-logits = TINV*pos
    const float term = (P * (LN2 * (gm + __log2f(gs))) - TINV * pos) / (P + 1e-8f);
    red[tid] = term * CLASS_COEF + noi * NOISE_RAW_COEF;
    __syncthreads();
    #pragma unroll
    for (int off = 128; off > 0; off >>= 1) {
        if (tid < off) red[tid] += red[tid + off];
        __syncthreads();
    }
    if (tid == 0) atomicAdd(out, red[0]);
}

extern "C" void kernel_launch(void* const* d_in, const int* in_sizes, int n_in,
                              void* d_out, int out_size, void* d_ws, size_t ws_size,
                              hipStream_t stream) {
    const float* feat  = (const float*)d_in[0];
    const int* labels  = (const int*)d_in[1];
    float* out = (float*)d_out;

    unsigned short* fbT = (unsigned short*)d_ws;                   // 2 MB bf16 transposed
    float* wsf    = (float*)((char*)d_ws + (size_t)NROWS * NDIM * 2);
    float* sM     = wsf;                    // 8192*16
    float* sS     = wsf + 131072;
    float* pcount = wsf + 262144;           // 512
    float* Ssum   = wsf + 262656;           // 16*128
    float* Bsum   = wsf + 264704;           // 512*128
    float* Gsum   = wsf + 330240;           // 1024*128

    hipLaunchKernelGGL(prep_kernel, dim3(512), dim3(256), 0, stream,
                       feat, labels, fbT, pcount, Ssum, out);
    hipLaunchKernelGGL(sums_kernel, dim3(128), dim3(256), 0, stream,
                       feat, labels, Bsum, Gsum, Ssum);
    hipLaunchKernelGGL(supcon_main, dim3(2048), dim3(256), 0, stream,
                       fbT, sM, sS);
    hipLaunchKernelGGL(final_k, dim3(32), dim3(256), 0, stream,
                       sM, sS, feat, labels, pcount, Bsum, Gsum, Ssum, out);
}